// Round 2
// baseline (1568.728 us; speedup 1.0000x reference)
//
#include <hip/hip_runtime.h>

typedef unsigned short u16;
typedef __attribute__((ext_vector_type(8))) short bf16x8;
typedef __attribute__((ext_vector_type(4))) float f32x4;

__device__ __forceinline__ u16 f2bf(float f) {
  unsigned u = __builtin_bit_cast(unsigned, f);
  u += 0x7fffu + ((u >> 16) & 1u);
  return (u16)(u >> 16);
}

__device__ __forceinline__ void gll16(const void* g, void* l) {
  __builtin_amdgcn_global_load_lds((const __attribute__((address_space(1))) void*)g,
                                   (__attribute__((address_space(3))) void*)l, 16, 0, 0);
}

// ---------------- bias concat: bc[1280] = [bq | bk | bv] ----------------
__global__ void build_bias_k(const float* __restrict__ bq, const float* __restrict__ bk,
                             const float* __restrict__ bv, float* __restrict__ bc) {
  int i = blockIdx.x * 256 + threadIdx.x;
  if (i < 1280) bc[i] = (i < 128) ? bq[i] : ((i < 256) ? bk[i - 128] : bv[i - 256]);
}

// ------- weight transpose: wt[n][f] bf16, n in [0,1280), f in [0,1024) -------
__global__ void transpose_w_k(const float* __restrict__ Wq, const float* __restrict__ Wk,
                              const float* __restrict__ Wv, u16* __restrict__ wt) {
  __shared__ float tile[64][65];
  const int n0 = blockIdx.x * 64;
  const int f0 = blockIdx.y * 64;
  const int t = threadIdx.x;
  const float* src; int ld, coff;
  if (n0 < 128)      { src = Wq; ld = 128;  coff = n0; }
  else if (n0 < 256) { src = Wk; ld = 128;  coff = n0 - 128; }
  else               { src = Wv; ld = 1024; coff = n0 - 256; }
  const int r = t >> 4, c4 = (t & 15) * 4;
  #pragma unroll
  for (int i = 0; i < 4; ++i) {
    float4 v = *(const float4*)(src + (size_t)(f0 + r + 16 * i) * ld + coff + c4);
    tile[r + 16 * i][c4 + 0] = v.x;
    tile[r + 16 * i][c4 + 1] = v.y;
    tile[r + 16 * i][c4 + 2] = v.z;
    tile[r + 16 * i][c4 + 3] = v.w;
  }
  __syncthreads();
  #pragma unroll
  for (int i = 0; i < 4; ++i) {
    const int nr = r + 16 * i;
    ushort4 h;
    h.x = f2bf(tile[c4 + 0][nr]);
    h.y = f2bf(tile[c4 + 1][nr]);
    h.z = f2bf(tile[c4 + 2][nr]);
    h.w = f2bf(tile[c4 + 3][nr]);
    *(ushort4*)(wt + (size_t)(n0 + nr) * 1024 + f0 + c4) = h;
  }
}

// ---------------- fused QKV GEMM: [32768,1024] @ [1024,1280] + bias ----------------
__global__ __launch_bounds__(256, 2) void gemm_qkv_k(
    const float* __restrict__ x, const u16* __restrict__ wt,
    const float* __restrict__ bc, u16* __restrict__ qkv, u16* __restrict__ vt) {
  __shared__ u16 sA[128 * 64];
  __shared__ u16 sB[128 * 64];
  char* sAc = (char*)sA;
  char* sBc = (char*)sB;
  const int t = threadIdx.x;
  const int w = t >> 6, lane = t & 63;
  const int wr = w >> 1, wc = w & 1;
  const int lm = lane & 15, lg = lane >> 4;
  const int m0 = blockIdx.x * 128;
  const f32x4 FZ = {0.f, 0.f, 0.f, 0.f};

  const int arow = t >> 4;
  const float* xb = x + (size_t)(m0 + arow) * 1024 + (t & 15) * 4;
  const int aswz = ((t >> 4) & 7) << 4;
  const int brow = t >> 3;
  const int bcol = 8 * ((t & 7) ^ ((t >> 3) & 7));
  const int kswz = (lm & 7) << 4;

  for (int nt = blockIdx.y * 5; nt < blockIdx.y * 5 + 5; ++nt) {
    const int n0 = nt * 128;
    f32x4 acc[4][4];
    #pragma unroll
    for (int mi = 0; mi < 4; ++mi)
      #pragma unroll
      for (int ni = 0; ni < 4; ++ni) acc[mi][ni] = FZ;
    const u16* wb = wt + (size_t)(n0 + brow) * 1024 + bcol;
    for (int kt = 0; kt < 16; ++kt) {
      const int k0 = kt * 64;
      #pragma unroll
      for (int i = 0; i < 8; ++i) {
        float4 v = *(const float4*)(xb + (size_t)(16 * i) * 1024 + k0);
        ushort4 h;
        h.x = f2bf(v.x); h.y = f2bf(v.y); h.z = f2bf(v.z); h.w = f2bf(v.w);
        *(ushort4*)(sAc + (((t + 256 * i) * 8) ^ aswz)) = h;
      }
      #pragma unroll
      for (int i = 0; i < 4; ++i)
        gll16(wb + (size_t)(32 * i) * 1024 + k0, sBc + w * 1024 + 4096 * i);
      __syncthreads();
      #pragma unroll
      for (int ks = 0; ks < 2; ++ks) {
        const int ka = (ks * 64 + lg * 16) ^ kswz;
        bf16x8 aF[4], bF[4];
        #pragma unroll
        for (int mi = 0; mi < 4; ++mi)
          aF[mi] = *(const bf16x8*)(sAc + (wr * 64 + mi * 16 + lm) * 128 + ka);
        #pragma unroll
        for (int ni = 0; ni < 4; ++ni)
          bF[ni] = *(const bf16x8*)(sBc + (wc * 64 + ni * 16 + lm) * 128 + ka);
        #pragma unroll
        for (int mi = 0; mi < 4; ++mi)
          #pragma unroll
          for (int ni = 0; ni < 4; ++ni)
            acc[mi][ni] = __builtin_amdgcn_mfma_f32_16x16x32_bf16(aF[mi], bF[ni], acc[mi][ni], 0, 0, 0);
      }
      __syncthreads();
    }
    #pragma unroll
    for (int ni = 0; ni < 4; ++ni) {
      const int col = n0 + wc * 64 + ni * 16 + lm;
      const float bias = bc[col];
      if (n0 < 256) {
        #pragma unroll
        for (int mi = 0; mi < 4; ++mi) {
          const int r0 = m0 + wr * 64 + mi * 16 + lg * 4;
          #pragma unroll
          for (int j = 0; j < 4; ++j)
            qkv[(size_t)(r0 + j) * 256 + col] = f2bf(acc[mi][ni][j] + bias);
        }
      } else {
        const int h = col - 256;
        #pragma unroll
        for (int mi = 0; mi < 4; ++mi) {
          const int r0 = m0 + wr * 64 + mi * 16 + lg * 4;
          const int bg = r0 >> 10;
          const int sb = r0 & 1023;
          ushort4 pk;
          pk.x = f2bf(acc[mi][ni][0] + bias);
          pk.y = f2bf(acc[mi][ni][1] + bias);
          pk.z = f2bf(acc[mi][ni][2] + bias);
          pk.w = f2bf(acc[mi][ni][3] + bias);
          *(ushort4*)(vt + ((size_t)(bg * 1024 + h) << 10) + sb) = pk;
        }
      }
    }
  }
}

// ---------------- flash attention + epilogue (gamma*O/l + x) ----------------
// 512 blocks (XCD-decoded), 512 threads = 8 waves: qw = w>>2 (32 q rows), hw = w&3 (256 h cols)
// Swapped QK^T (mfma(K,Q)): lane holds S[kv=lg*4+j(+16ch)][q=lm] -> in-register softmax.
// Leader wave (hw==0) of each qw group writes the shared P buffer.
__global__ __launch_bounds__(512, 4) void attn_k(
    const u16* __restrict__ qk, const u16* __restrict__ vt,
    const float* __restrict__ x, const float* __restrict__ gam,
    float* __restrict__ out) {
  __shared__ u16 sK[32 * 128];   // 8 KB, rows 256B, XOR-swizzled by (row&7)<<4
  __shared__ u16 sV[1024 * 32];  // 64 KB, rows 64B, chunk-swizzled by ((row>>1)&3)<<4
  __shared__ u16 sP[2 * 32 * 32]; // 4 KB, two 32x32 P buffers, same chunk swizzle
  char* sKc = (char*)sK;
  char* sVc = (char*)sV;
  char* sPc = (char*)sP;
  const int t = threadIdx.x;
  const int w = t >> 6, lane = t & 63;
  const int qw = w >> 2, hw = w & 3;
  const int lm = lane & 15, lg = lane >> 4;
  const bool leader = (hw == 0);
  // XCD-aware decode: 16 qt-blocks of a bg land on one XCD
  const int bid = blockIdx.x;
  const int qt = (bid >> 3) & 15;
  const int bg = (((bid >> 7) & 3) << 3) | (bid & 7);
  const f32x4 FZ = {0.f, 0.f, 0.f, 0.f};
  const int swzb = ((lm >> 1) & 3) << 4;

  // Q fragments (B operand): row = lm (q), k = lg*8+i
  bf16x8 qf[2][4];
  #pragma unroll
  for (int f = 0; f < 2; ++f)
    #pragma unroll
    for (int ks = 0; ks < 4; ++ks)
      qf[f][ks] = *(const bf16x8*)(qk +
          (size_t)(bg * 1024 + qt * 64 + qw * 32 + f * 16 + lm) * 256 + ks * 32 + lg * 8);

  f32x4 oacc[2][16];
  #pragma unroll
  for (int f = 0; f < 2; ++f)
    #pragma unroll
    for (int hc = 0; hc < 16; ++hc) oacc[f][hc] = FZ;
  float m_run[2] = {-3e38f, -3e38f}, l_run[2] = {0.f, 0.f};

  const char* qkc = (const char*)qk;
  const char* vtc = (const char*)vt;
  const int krow = t >> 4;
  const char* ksrc = qkc + (size_t)(bg * 1024 + krow) * 512 + 256 + (((t & 15) ^ (krow & 7)) << 4);
  const char* vsrc = vtc + ((size_t)(bg * 1024 + (t >> 2))) * 2048 + (((t & 3) ^ ((t >> 3) & 3)) << 4);

  for (int kv0 = 0; kv0 < 1024; kv0 += 32) {
    __syncthreads();  // previous iteration done reading sK/sV/sP
    gll16(ksrc + (size_t)kv0 * 512, sKc + w * 1024);
    #pragma unroll
    for (int i = 0; i < 8; ++i)
      gll16(vsrc + (size_t)kv0 * 2 + 262144 * i, sVc + w * 1024 + 8192 * i);
    __syncthreads();  // tiles visible (vmcnt drained by barrier)

    // S^T = K @ Q^T  (swapped operands)
    f32x4 sc[2][2];
    sc[0][0] = FZ; sc[0][1] = FZ; sc[1][0] = FZ; sc[1][1] = FZ;
    #pragma unroll
    for (int ch = 0; ch < 2; ++ch)
      #pragma unroll
      for (int ks = 0; ks < 4; ++ks) {
        bf16x8 kf = *(const bf16x8*)(sKc + (ch * 16 + lm) * 256 + ((ks * 64 + lg * 16) ^ ((lm & 7) << 4)));
        sc[0][ch] = __builtin_amdgcn_mfma_f32_16x16x32_bf16(kf, qf[0][ks], sc[0][ch], 0, 0, 0);
        sc[1][ch] = __builtin_amdgcn_mfma_f32_16x16x32_bf16(kf, qf[1][ks], sc[1][ch], 0, 0, 0);
      }

    // in-register online softmax (per-lane column q=lm; reduce across lg via 2 shuffles)
    float pm[2];
    #pragma unroll
    for (int f = 0; f < 2; ++f) {
      float a0 = fmaxf(fmaxf(sc[f][0][0], sc[f][0][1]), fmaxf(sc[f][0][2], sc[f][0][3]));
      float a1 = fmaxf(fmaxf(sc[f][1][0], sc[f][1][1]), fmaxf(sc[f][1][2], sc[f][1][3]));
      float m8 = fmaxf(a0, a1);
      m8 = fmaxf(m8, __shfl_xor(m8, 16));
      m8 = fmaxf(m8, __shfl_xor(m8, 32));
      pm[f] = m8;
    }
    const bool grow = (pm[0] > m_run[0] + 8.0f) | (pm[1] > m_run[1] + 8.0f);
    if (__any(grow)) {  // defer-max rescale (rare)
      #pragma unroll
      for (int f = 0; f < 2; ++f) {
        const float mn = fmaxf(m_run[f], pm[f]);
        const float alf = __expf(m_run[f] - mn);
        m_run[f] = mn;
        l_run[f] *= alf;
        float ab[4];
        #pragma unroll
        for (int j = 0; j < 4; ++j) ab[j] = __shfl(alf, lg * 4 + j);
        #pragma unroll
        for (int hc = 0; hc < 16; ++hc)
          #pragma unroll
          for (int j = 0; j < 4; ++j) oacc[f][hc][j] *= ab[j];
      }
    }
    #pragma unroll
    for (int f = 0; f < 2; ++f) {
      float p0[4], p1[4];
      #pragma unroll
      for (int j = 0; j < 4; ++j) {
        p0[j] = __expf(sc[f][0][j] - m_run[f]);
        p1[j] = __expf(sc[f][1][j] - m_run[f]);
      }
      float rs = ((p0[0] + p0[1]) + (p0[2] + p0[3])) + ((p1[0] + p1[1]) + (p1[2] + p1[3]));
      rs += __shfl_xor(rs, 16);
      rs += __shfl_xor(rs, 32);
      l_run[f] += rs;
      if (leader) {  // write P[q][kv] (A-layout) to shared buffer, chunk-swizzled
        ushort4 u0, u1;
        u0.x = f2bf(p0[0]); u0.y = f2bf(p0[1]); u0.z = f2bf(p0[2]); u0.w = f2bf(p0[3]);
        u1.x = f2bf(p1[0]); u1.y = f2bf(p1[1]); u1.z = f2bf(p1[2]); u1.w = f2bf(p1[3]);
        char* pb = sPc + qw * 2048 + (f * 16 + lm) * 64;
        *(ushort4*)(pb + ((lg * 8) ^ swzb)) = u0;
        *(ushort4*)(pb + ((32 + lg * 8) ^ swzb)) = u1;
      }
    }
    __syncthreads();  // P visible

    // O += P @ V   (vf reused across both P fragments)
    bf16x8 pa0 = *(const bf16x8*)(sPc + qw * 2048 + lm * 64 + ((lg * 16) ^ swzb));
    bf16x8 pa1 = *(const bf16x8*)(sPc + qw * 2048 + (16 + lm) * 64 + ((lg * 16) ^ swzb));
    #pragma unroll
    for (int hc = 0; hc < 16; ++hc) {
      bf16x8 vf = *(const bf16x8*)(sVc + (hw * 256 + hc * 16 + lm) * 64 + ((lg * 16) ^ swzb));
      oacc[0][hc] = __builtin_amdgcn_mfma_f32_16x16x32_bf16(pa0, vf, oacc[0][hc], 0, 0, 0);
      oacc[1][hc] = __builtin_amdgcn_mfma_f32_16x16x32_bf16(pa1, vf, oacc[1][hc], 0, 0, 0);
    }
  }

  // epilogue: out = gamma * O/l + x
  const float g0 = gam[0];
  #pragma unroll
  for (int f = 0; f < 2; ++f) {
    float inv[4];
    #pragma unroll
    for (int j = 0; j < 4; ++j) inv[j] = 1.0f / __shfl(l_run[f], lg * 4 + j);
    #pragma unroll
    for (int j = 0; j < 4; ++j) {
      const size_t ro = (size_t)(bg * 1024 + qt * 64 + qw * 32 + f * 16 + lg * 4 + j) * 1024;
      #pragma unroll
      for (int hc = 0; hc < 16; ++hc) {
        const int col = hw * 256 + hc * 16 + lm;
        out[ro + col] = g0 * oacc[f][hc][j] * inv[j] + x[ro + col];
      }
    }
  }
}

extern "C" void kernel_launch(void* const* d_in, const int* in_sizes, int n_in,
                              void* d_out, int out_size, void* d_ws, size_t ws_size,
                              hipStream_t stream) {
  const float* x  = (const float*)d_in[0];
  const float* Wq = (const float*)d_in[1];
  const float* bq = (const float*)d_in[2];
  const float* Wk = (const float*)d_in[3];
  const float* bk = (const float*)d_in[4];
  const float* Wv = (const float*)d_in[5];
  const float* bv = (const float*)d_in[6];
  const float* gm = (const float*)d_in[7];
  float* out = (float*)d_out;

  char* ws = (char*)d_ws;
  u16*   wt = (u16*)(ws);                 // 2,621,440 B
  float* bc = (float*)(ws + 2621440);     // 5,120 B
  u16*   qk = (u16*)(ws + 2626560);       // 16,777,216 B
  u16*   vt = (u16*)(ws + 19403776);      // 67,108,864 B

  build_bias_k<<<5, 256, 0, stream>>>(bq, bk, bv, bc);
  transpose_w_k<<<dim3(20, 16), 256, 0, stream>>>(Wq, Wk, Wv, wt);
  gemm_qkv_k<<<dim3(256, 2), 256, 0, stream>>>(x, wt, bc, qk, vt);
  attn_k<<<dim3(512), 512, 0, stream>>>(qk, vt, x, gm, out);
}

// Round 3
// 412.282 us; speedup vs baseline: 3.8050x; 3.8050x over previous
//
#include <hip/hip_runtime.h>

typedef unsigned short u16;
typedef __attribute__((ext_vector_type(8))) short bf16x8;
typedef __attribute__((ext_vector_type(4))) float f32x4;
typedef __attribute__((ext_vector_type(4))) unsigned int u32x4;

__device__ __forceinline__ u16 f2bf(float f) {
  unsigned u = __builtin_bit_cast(unsigned, f);
  u += 0x7fffu + ((u >> 16) & 1u);
  return (u16)(u >> 16);
}

__device__ __forceinline__ unsigned pkbf(float lo, float hi) {
  unsigned r;
  asm("v_cvt_pk_bf16_f32 %0, %1, %2" : "=v"(r) : "v"(lo), "v"(hi));
  return r;
}

__device__ __forceinline__ void gll16(const void* g, void* l) {
  __builtin_amdgcn_global_load_lds((const __attribute__((address_space(1))) void*)g,
                                   (__attribute__((address_space(3))) void*)l, 16, 0, 0);
}

// ---------------- bias concat: bc[1280] = [bq | bk | bv] ----------------
__global__ void build_bias_k(const float* __restrict__ bq, const float* __restrict__ bk,
                             const float* __restrict__ bv, float* __restrict__ bc) {
  int i = blockIdx.x * 256 + threadIdx.x;
  if (i < 1280) bc[i] = (i < 128) ? bq[i] : ((i < 256) ? bk[i - 128] : bv[i - 256]);
}

// ------- weight transpose: wt[n][f] bf16, n in [0,1280), f in [0,1024) -------
__global__ void transpose_w_k(const float* __restrict__ Wq, const float* __restrict__ Wk,
                              const float* __restrict__ Wv, u16* __restrict__ wt) {
  __shared__ float tile[64][65];
  const int n0 = blockIdx.x * 64;
  const int f0 = blockIdx.y * 64;
  const int t = threadIdx.x;
  const float* src; int ld, coff;
  if (n0 < 128)      { src = Wq; ld = 128;  coff = n0; }
  else if (n0 < 256) { src = Wk; ld = 128;  coff = n0 - 128; }
  else               { src = Wv; ld = 1024; coff = n0 - 256; }
  const int r = t >> 4, c4 = (t & 15) * 4;
  #pragma unroll
  for (int i = 0; i < 4; ++i) {
    float4 v = *(const float4*)(src + (size_t)(f0 + r + 16 * i) * ld + coff + c4);
    tile[r + 16 * i][c4 + 0] = v.x;
    tile[r + 16 * i][c4 + 1] = v.y;
    tile[r + 16 * i][c4 + 2] = v.z;
    tile[r + 16 * i][c4 + 3] = v.w;
  }
  __syncthreads();
  #pragma unroll
  for (int i = 0; i < 4; ++i) {
    const int nr = r + 16 * i;
    ushort4 h;
    h.x = f2bf(tile[c4 + 0][nr]);
    h.y = f2bf(tile[c4 + 1][nr]);
    h.z = f2bf(tile[c4 + 2][nr]);
    h.w = f2bf(tile[c4 + 3][nr]);
    *(ushort4*)(wt + (size_t)(n0 + nr) * 1024 + f0 + c4) = h;
  }
}

// ---------------- fused QKV GEMM: [32768,1024] @ [1024,1280] + bias ----------------
__global__ __launch_bounds__(256, 2) void gemm_qkv_k(
    const float* __restrict__ x, const u16* __restrict__ wt,
    const float* __restrict__ bc, u16* __restrict__ qkv, u16* __restrict__ vt) {
  __shared__ u16 sA[128 * 64];
  __shared__ u16 sB[128 * 64];
  char* sAc = (char*)sA;
  char* sBc = (char*)sB;
  const int t = threadIdx.x;
  const int w = t >> 6, lane = t & 63;
  const int wr = w >> 1, wc = w & 1;
  const int lm = lane & 15, lg = lane >> 4;
  const int m0 = blockIdx.x * 128;
  const f32x4 FZ = {0.f, 0.f, 0.f, 0.f};

  const int arow = t >> 4;
  const float* xb = x + (size_t)(m0 + arow) * 1024 + (t & 15) * 4;
  const int aswz = ((t >> 4) & 7) << 4;
  const int brow = t >> 3;
  const int bcol = 8 * ((t & 7) ^ ((t >> 3) & 7));
  const int kswz = (lm & 7) << 4;

  for (int nt = blockIdx.y * 5; nt < blockIdx.y * 5 + 5; ++nt) {
    const int n0 = nt * 128;
    f32x4 acc[4][4];
    #pragma unroll
    for (int mi = 0; mi < 4; ++mi)
      #pragma unroll
      for (int ni = 0; ni < 4; ++ni) acc[mi][ni] = FZ;
    const u16* wb = wt + (size_t)(n0 + brow) * 1024 + bcol;
    for (int kt = 0; kt < 16; ++kt) {
      const int k0 = kt * 64;
      #pragma unroll
      for (int i = 0; i < 8; ++i) {
        float4 v = *(const float4*)(xb + (size_t)(16 * i) * 1024 + k0);
        ushort4 h;
        h.x = f2bf(v.x); h.y = f2bf(v.y); h.z = f2bf(v.z); h.w = f2bf(v.w);
        *(ushort4*)(sAc + (((t + 256 * i) * 8) ^ aswz)) = h;
      }
      #pragma unroll
      for (int i = 0; i < 4; ++i)
        gll16(wb + (size_t)(32 * i) * 1024 + k0, sBc + w * 1024 + 4096 * i);
      __syncthreads();
      #pragma unroll
      for (int ks = 0; ks < 2; ++ks) {
        const int ka = (ks * 64 + lg * 16) ^ kswz;
        bf16x8 aF[4], bF[4];
        #pragma unroll
        for (int mi = 0; mi < 4; ++mi)
          aF[mi] = *(const bf16x8*)(sAc + (wr * 64 + mi * 16 + lm) * 128 + ka);
        #pragma unroll
        for (int ni = 0; ni < 4; ++ni)
          bF[ni] = *(const bf16x8*)(sBc + (wc * 64 + ni * 16 + lm) * 128 + ka);
        #pragma unroll
        for (int mi = 0; mi < 4; ++mi)
          #pragma unroll
          for (int ni = 0; ni < 4; ++ni)
            acc[mi][ni] = __builtin_amdgcn_mfma_f32_16x16x32_bf16(aF[mi], bF[ni], acc[mi][ni], 0, 0, 0);
      }
      __syncthreads();
    }
    #pragma unroll
    for (int ni = 0; ni < 4; ++ni) {
      const int col = n0 + wc * 64 + ni * 16 + lm;
      const float bias = bc[col];
      if (n0 < 256) {
        #pragma unroll
        for (int mi = 0; mi < 4; ++mi) {
          const int r0 = m0 + wr * 64 + mi * 16 + lg * 4;
          #pragma unroll
          for (int j = 0; j < 4; ++j)
            qkv[(size_t)(r0 + j) * 256 + col] = f2bf(acc[mi][ni][j] + bias);
        }
      } else {
        const int h = col - 256;
        #pragma unroll
        for (int mi = 0; mi < 4; ++mi) {
          const int r0 = m0 + wr * 64 + mi * 16 + lg * 4;
          const int bg = r0 >> 10;
          const int sb = r0 & 1023;
          ushort4 pk;
          pk.x = f2bf(acc[mi][ni][0] + bias);
          pk.y = f2bf(acc[mi][ni][1] + bias);
          pk.z = f2bf(acc[mi][ni][2] + bias);
          pk.w = f2bf(acc[mi][ni][3] + bias);
          *(ushort4*)(vt + ((size_t)(bg * 1024 + h) << 10) + sb) = pk;
        }
      }
    }
  }
}

// ---------------- flash attention + epilogue (gamma*O/l + x) ----------------
// 512 blocks (XCD-decoded), 512 threads = 8 waves: qw = w>>2 (32 q rows), hw = w&3 (256 h cols)
// Swapped QK^T (mfma(K,Q)): lane holds S[kv=ch*16+lg*4+j][q=lm].
// P -> PV A-fragment built fully in-register (cvt_pk + 8 shfl), no LDS bounce, 2 barriers/step.
__global__ __launch_bounds__(512, 2) void attn_k(
    const u16* __restrict__ qk, const u16* __restrict__ vt,
    const float* __restrict__ x, const float* __restrict__ gam,
    float* __restrict__ out) {
  __shared__ u16 sK[32 * 128];   // 8 KB, rows 256B, XOR-swizzled by (row&7)<<4
  __shared__ u16 sV[1024 * 32];  // 64 KB, rows 64B, chunk-swizzled by ((row>>1)&3)<<4
  char* sKc = (char*)sK;
  char* sVc = (char*)sV;
  const int t = threadIdx.x;
  const int w = t >> 6, lane = t & 63;
  const int qw = w >> 2, hw = w & 3;
  const int lm = lane & 15, lg = lane >> 4;
  const int bid = blockIdx.x;
  const int qt = (bid >> 3) & 15;
  const int bg = (((bid >> 7) & 3) << 3) | (bid & 7);
  const f32x4 FZ = {0.f, 0.f, 0.f, 0.f};
  const int swzb = ((lm >> 1) & 3) << 4;

  // Q fragments (B operand): col = lm (q), k = lg*8+i
  bf16x8 qf[2][4];
  #pragma unroll
  for (int f = 0; f < 2; ++f)
    #pragma unroll
    for (int ks = 0; ks < 4; ++ks)
      qf[f][ks] = *(const bf16x8*)(qk +
          (size_t)(bg * 1024 + qt * 64 + qw * 32 + f * 16 + lm) * 256 + ks * 32 + lg * 8);

  f32x4 oacc[2][16];
  #pragma unroll
  for (int f = 0; f < 2; ++f)
    #pragma unroll
    for (int hc = 0; hc < 16; ++hc) oacc[f][hc] = FZ;
  float m_run[2] = {-3e38f, -3e38f}, l_run[2] = {0.f, 0.f};

  const char* qkc = (const char*)qk;
  const char* vtc = (const char*)vt;
  const int krow = t >> 4;
  const char* ksrc = qkc + (size_t)(bg * 1024 + krow) * 512 + 256 + (((t & 15) ^ (krow & 7)) << 4);
  const char* vsrc = vtc + ((size_t)(bg * 1024 + (t >> 2))) * 2048 + (((t & 3) ^ ((t >> 3) & 3)) << 4);
  const int src0 = (2 * (lg & 1)) * 16 + lm;   // shuffle sources for P transform
  const int src1 = src0 + 16;
  const bool chlo = (lg < 2);

  for (int kv0 = 0; kv0 < 1024; kv0 += 32) {
    __syncthreads();  // previous iteration done reading sK/sV
    gll16(ksrc + (size_t)kv0 * 512, sKc + w * 1024);
    #pragma unroll
    for (int i = 0; i < 8; ++i)
      gll16(vsrc + (size_t)kv0 * 2 + 262144 * i, sVc + w * 1024 + 8192 * i);
    __syncthreads();  // tiles visible (vmcnt drained by barrier)

    // S^T = K @ Q^T  (swapped operands)
    f32x4 sc[2][2];
    sc[0][0] = FZ; sc[0][1] = FZ; sc[1][0] = FZ; sc[1][1] = FZ;
    #pragma unroll
    for (int ch = 0; ch < 2; ++ch)
      #pragma unroll
      for (int ks = 0; ks < 4; ++ks) {
        bf16x8 kf = *(const bf16x8*)(sKc + (ch * 16 + lm) * 256 + ((ks * 64 + lg * 16) ^ ((lm & 7) << 4)));
        sc[0][ch] = __builtin_amdgcn_mfma_f32_16x16x32_bf16(kf, qf[0][ks], sc[0][ch], 0, 0, 0);
        sc[1][ch] = __builtin_amdgcn_mfma_f32_16x16x32_bf16(kf, qf[1][ks], sc[1][ch], 0, 0, 0);
      }

    // in-register online softmax (per-lane column q=lm; reduce across lg via 2 shuffles)
    float pm[2];
    #pragma unroll
    for (int f = 0; f < 2; ++f) {
      float a0 = fmaxf(fmaxf(sc[f][0][0], sc[f][0][1]), fmaxf(sc[f][0][2], sc[f][0][3]));
      float a1 = fmaxf(fmaxf(sc[f][1][0], sc[f][1][1]), fmaxf(sc[f][1][2], sc[f][1][3]));
      float m8 = fmaxf(a0, a1);
      m8 = fmaxf(m8, __shfl_xor(m8, 16));
      m8 = fmaxf(m8, __shfl_xor(m8, 32));
      pm[f] = m8;
    }
    const bool grow = (pm[0] > m_run[0] + 8.0f) | (pm[1] > m_run[1] + 8.0f);
    if (__any(grow)) {  // defer-max rescale (rare)
      #pragma unroll
      for (int f = 0; f < 2; ++f) {
        const float mn = fmaxf(m_run[f], pm[f]);
        const float alf = __expf(m_run[f] - mn);
        m_run[f] = mn;
        l_run[f] *= alf;
        float ab[4];
        #pragma unroll
        for (int j = 0; j < 4; ++j) ab[j] = __shfl(alf, lg * 4 + j);
        #pragma unroll
        for (int hc = 0; hc < 16; ++hc)
          #pragma unroll
          for (int j = 0; j < 4; ++j) oacc[f][hc][j] *= ab[j];
      }
    }

    // P = exp(S - m), row-sum, and in-register D->A transform (no LDS, no barrier)
    bf16x8 pa[2];
    #pragma unroll
    for (int f = 0; f < 2; ++f) {
      float p0[4], p1[4];
      #pragma unroll
      for (int j = 0; j < 4; ++j) {
        p0[j] = __expf(sc[f][0][j] - m_run[f]);
        p1[j] = __expf(sc[f][1][j] - m_run[f]);
      }
      float rs = ((p0[0] + p0[1]) + (p0[2] + p0[3])) + ((p1[0] + p1[1]) + (p1[2] + p1[3]));
      rs += __shfl_xor(rs, 16);
      rs += __shfl_xor(rs, 32);
      l_run[f] += rs;
      // lane holds P[kv=ch*16+lg*4+j][q=lm]; target lane needs P[q=lm][kv=lg*8+i]
      unsigned c0 = pkbf(p0[0], p0[1]);  // kv = lg*4+{0,1}
      unsigned c1 = pkbf(p0[2], p0[3]);  // kv = lg*4+{2,3}
      unsigned c2 = pkbf(p1[0], p1[1]);  // kv = 16+lg*4+{0,1}
      unsigned c3 = pkbf(p1[2], p1[3]);  // kv = 16+lg*4+{2,3}
      unsigned a0 = __shfl(c0, src0), b0 = __shfl(c2, src0);
      unsigned a1 = __shfl(c1, src0), b1 = __shfl(c3, src0);
      unsigned a2 = __shfl(c0, src1), b2 = __shfl(c2, src1);
      unsigned a3 = __shfl(c1, src1), b3 = __shfl(c3, src1);
      u32x4 pw;
      pw.x = chlo ? a0 : b0;  // kv = 8lg+{0,1}
      pw.y = chlo ? a1 : b1;  // kv = 8lg+{2,3}
      pw.z = chlo ? a2 : b2;  // kv = 8lg+{4,5}
      pw.w = chlo ? a3 : b3;  // kv = 8lg+{6,7}
      pa[f] = __builtin_bit_cast(bf16x8, pw);
    }

    // O += P @ V   (vf reused across both P fragments)
    #pragma unroll
    for (int hc = 0; hc < 16; ++hc) {
      bf16x8 vf = *(const bf16x8*)(sVc + (hw * 256 + hc * 16 + lm) * 64 + ((lg * 16) ^ swzb));
      oacc[0][hc] = __builtin_amdgcn_mfma_f32_16x16x32_bf16(pa[0], vf, oacc[0][hc], 0, 0, 0);
      oacc[1][hc] = __builtin_amdgcn_mfma_f32_16x16x32_bf16(pa[1], vf, oacc[1][hc], 0, 0, 0);
    }
  }

  // epilogue: out = gamma * O/l + x
  const float g0 = gam[0];
  #pragma unroll
  for (int f = 0; f < 2; ++f) {
    float inv[4];
    #pragma unroll
    for (int j = 0; j < 4; ++j) inv[j] = 1.0f / __shfl(l_run[f], lg * 4 + j);
    #pragma unroll
    for (int j = 0; j < 4; ++j) {
      const size_t ro = (size_t)(bg * 1024 + qt * 64 + qw * 32 + f * 16 + lg * 4 + j) * 1024;
      #pragma unroll
      for (int hc = 0; hc < 16; ++hc) {
        const int col = hw * 256 + hc * 16 + lm;
        out[ro + col] = g0 * oacc[f][hc][j] * inv[j] + x[ro + col];
      }
    }
  }
}

extern "C" void kernel_launch(void* const* d_in, const int* in_sizes, int n_in,
                              void* d_out, int out_size, void* d_ws, size_t ws_size,
                              hipStream_t stream) {
  const float* x  = (const float*)d_in[0];
  const float* Wq = (const float*)d_in[1];
  const float* bq = (const float*)d_in[2];
  const float* Wk = (const float*)d_in[3];
  const float* bk = (const float*)d_in[4];
  const float* Wv = (const float*)d_in[5];
  const float* bv = (const float*)d_in[6];
  const float* gm = (const float*)d_in[7];
  float* out = (float*)d_out;

  char* ws = (char*)d_ws;
  u16*   wt = (u16*)(ws);                 // 2,621,440 B
  float* bc = (float*)(ws + 2621440);     // 5,120 B
  u16*   qk = (u16*)(ws + 2626560);       // 16,777,216 B
  u16*   vt = (u16*)(ws + 19403776);      // 67,108,864 B

  build_bias_k<<<5, 256, 0, stream>>>(bq, bk, bv, bc);
  transpose_w_k<<<dim3(20, 16), 256, 0, stream>>>(Wq, Wk, Wv, wt);
  gemm_qkv_k<<<dim3(256, 2), 256, 0, stream>>>(x, wt, bc, qk, vt);
  attn_k<<<dim3(512), 512, 0, stream>>>(qk, vt, x, gm, out);
}

// Round 4
// 394.039 us; speedup vs baseline: 3.9811x; 1.0463x over previous
//
#include <hip/hip_runtime.h>

typedef unsigned short u16;
typedef __attribute__((ext_vector_type(8))) short bf16x8;
typedef __attribute__((ext_vector_type(4))) float f32x4;
typedef __attribute__((ext_vector_type(4))) unsigned int u32x4;

__device__ __forceinline__ u16 f2bf(float f) {
  unsigned u = __builtin_bit_cast(unsigned, f);
  u += 0x7fffu + ((u >> 16) & 1u);
  return (u16)(u >> 16);
}

__device__ __forceinline__ unsigned pkbf(float lo, float hi) {
  unsigned r;
  asm("v_cvt_pk_bf16_f32 %0, %1, %2" : "=v"(r) : "v"(lo), "v"(hi));
  return r;
}

__device__ __forceinline__ void gll16(const void* g, void* l) {
  __builtin_amdgcn_global_load_lds((const __attribute__((address_space(1))) void*)g,
                                   (__attribute__((address_space(3))) void*)l, 16, 0, 0);
}

// ---------------- bias concat: bc[1280] = [bq | bk | bv] ----------------
__global__ void build_bias_k(const float* __restrict__ bq, const float* __restrict__ bk,
                             const float* __restrict__ bv, float* __restrict__ bc) {
  int i = blockIdx.x * 256 + threadIdx.x;
  if (i < 1280) bc[i] = (i < 128) ? bq[i] : ((i < 256) ? bk[i - 128] : bv[i - 256]);
}

// ------- weight transpose: wt[n][f] bf16, n in [0,1280), f in [0,1024) -------
__global__ void transpose_w_k(const float* __restrict__ Wq, const float* __restrict__ Wk,
                              const float* __restrict__ Wv, u16* __restrict__ wt) {
  __shared__ float tile[64][65];
  const int n0 = blockIdx.x * 64;
  const int f0 = blockIdx.y * 64;
  const int t = threadIdx.x;
  const float* src; int ld, coff;
  if (n0 < 128)      { src = Wq; ld = 128;  coff = n0; }
  else if (n0 < 256) { src = Wk; ld = 128;  coff = n0 - 128; }
  else               { src = Wv; ld = 1024; coff = n0 - 256; }
  const int r = t >> 4, c4 = (t & 15) * 4;
  #pragma unroll
  for (int i = 0; i < 4; ++i) {
    float4 v = *(const float4*)(src + (size_t)(f0 + r + 16 * i) * ld + coff + c4);
    tile[r + 16 * i][c4 + 0] = v.x;
    tile[r + 16 * i][c4 + 1] = v.y;
    tile[r + 16 * i][c4 + 2] = v.z;
    tile[r + 16 * i][c4 + 3] = v.w;
  }
  __syncthreads();
  #pragma unroll
  for (int i = 0; i < 4; ++i) {
    const int nr = r + 16 * i;
    ushort4 h;
    h.x = f2bf(tile[c4 + 0][nr]);
    h.y = f2bf(tile[c4 + 1][nr]);
    h.z = f2bf(tile[c4 + 2][nr]);
    h.w = f2bf(tile[c4 + 3][nr]);
    *(ushort4*)(wt + (size_t)(n0 + nr) * 1024 + f0 + c4) = h;
  }
}

// ---------------- fused QKV GEMM: [32768,1024] @ [1024,1280] + bias ----------------
__global__ __launch_bounds__(256, 2) void gemm_qkv_k(
    const float* __restrict__ x, const u16* __restrict__ wt,
    const float* __restrict__ bc, u16* __restrict__ qkv, u16* __restrict__ vt) {
  __shared__ u16 sA[128 * 64];
  __shared__ u16 sB[128 * 64];
  char* sAc = (char*)sA;
  char* sBc = (char*)sB;
  const int t = threadIdx.x;
  const int w = t >> 6, lane = t & 63;
  const int wr = w >> 1, wc = w & 1;
  const int lm = lane & 15, lg = lane >> 4;
  const int m0 = blockIdx.x * 128;
  const f32x4 FZ = {0.f, 0.f, 0.f, 0.f};

  const int arow = t >> 4;
  const float* xb = x + (size_t)(m0 + arow) * 1024 + (t & 15) * 4;
  const int aswz = ((t >> 4) & 7) << 4;
  const int brow = t >> 3;
  const int bcol = 8 * ((t & 7) ^ ((t >> 3) & 7));
  const int kswz = (lm & 7) << 4;

  for (int nt = blockIdx.y * 5; nt < blockIdx.y * 5 + 5; ++nt) {
    const int n0 = nt * 128;
    f32x4 acc[4][4];
    #pragma unroll
    for (int mi = 0; mi < 4; ++mi)
      #pragma unroll
      for (int ni = 0; ni < 4; ++ni) acc[mi][ni] = FZ;
    const u16* wb = wt + (size_t)(n0 + brow) * 1024 + bcol;
    for (int kt = 0; kt < 16; ++kt) {
      const int k0 = kt * 64;
      #pragma unroll
      for (int i = 0; i < 8; ++i) {
        float4 v = *(const float4*)(xb + (size_t)(16 * i) * 1024 + k0);
        ushort4 h;
        h.x = f2bf(v.x); h.y = f2bf(v.y); h.z = f2bf(v.z); h.w = f2bf(v.w);
        *(ushort4*)(sAc + (((t + 256 * i) * 8) ^ aswz)) = h;
      }
      #pragma unroll
      for (int i = 0; i < 4; ++i)
        gll16(wb + (size_t)(32 * i) * 1024 + k0, sBc + w * 1024 + 4096 * i);
      __syncthreads();
      #pragma unroll
      for (int ks = 0; ks < 2; ++ks) {
        const int ka = (ks * 64 + lg * 16) ^ kswz;
        bf16x8 aF[4], bF[4];
        #pragma unroll
        for (int mi = 0; mi < 4; ++mi)
          aF[mi] = *(const bf16x8*)(sAc + (wr * 64 + mi * 16 + lm) * 128 + ka);
        #pragma unroll
        for (int ni = 0; ni < 4; ++ni)
          bF[ni] = *(const bf16x8*)(sBc + (wc * 64 + ni * 16 + lm) * 128 + ka);
        #pragma unroll
        for (int mi = 0; mi < 4; ++mi)
          #pragma unroll
          for (int ni = 0; ni < 4; ++ni)
            acc[mi][ni] = __builtin_amdgcn_mfma_f32_16x16x32_bf16(aF[mi], bF[ni], acc[mi][ni], 0, 0, 0);
      }
      __syncthreads();
    }
    #pragma unroll
    for (int ni = 0; ni < 4; ++ni) {
      const int col = n0 + wc * 64 + ni * 16 + lm;
      const float bias = bc[col];
      if (n0 < 256) {
        #pragma unroll
        for (int mi = 0; mi < 4; ++mi) {
          const int r0 = m0 + wr * 64 + mi * 16 + lg * 4;
          #pragma unroll
          for (int j = 0; j < 4; ++j)
            qkv[(size_t)(r0 + j) * 256 + col] = f2bf(acc[mi][ni][j] + bias);
        }
      } else {
        const int h = col - 256;
        #pragma unroll
        for (int mi = 0; mi < 4; ++mi) {
          const int r0 = m0 + wr * 64 + mi * 16 + lg * 4;
          const int bg = r0 >> 10;
          const int sb = r0 & 1023;
          ushort4 pk;
          pk.x = f2bf(acc[mi][ni][0] + bias);
          pk.y = f2bf(acc[mi][ni][1] + bias);
          pk.z = f2bf(acc[mi][ni][2] + bias);
          pk.w = f2bf(acc[mi][ni][3] + bias);
          *(ushort4*)(vt + ((size_t)(bg * 1024 + h) << 10) + sb) = pk;
        }
      }
    }
  }
}

// ---------------- flash attention + epilogue (gamma*O/l + x) ----------------
// 512 blocks (XCD-decoded), 512 threads = 8 waves: qw = w>>2 (32 q rows), hw = w&3 (256 h cols)
// Swapped QK^T; in-register P transform; DOUBLE-BUFFERED K/V with counted vmcnt(9):
// next tile's 9 gll16/wave stay in flight across the whole compute phase (T3-lite).
__global__ __launch_bounds__(512, 2) void attn_k(
    const u16* __restrict__ qk, const u16* __restrict__ vt,
    const float* __restrict__ x, const float* __restrict__ gam,
    float* __restrict__ out) {
  __shared__ u16 sK[2 * 32 * 128];   // 16 KB, rows 256B, XOR-swizzled by (row&7)<<4
  __shared__ u16 sV[2 * 1024 * 32];  // 128 KB, rows 64B, chunk-swizzled by ((row>>1)&3)<<4
  char* sKc = (char*)sK;
  char* sVc = (char*)sV;
  const int t = threadIdx.x;
  const int w = t >> 6, lane = t & 63;
  const int qw = w >> 2, hw = w & 3;
  const int lm = lane & 15, lg = lane >> 4;
  const int bid = blockIdx.x;
  const int qt = (bid >> 3) & 15;
  const int bg = (((bid >> 7) & 3) << 3) | (bid & 7);
  const f32x4 FZ = {0.f, 0.f, 0.f, 0.f};
  const int swzb = ((lm >> 1) & 3) << 4;

  // Q fragments (B operand): col = lm (q), k = lg*8+i
  bf16x8 qf[2][4];
  #pragma unroll
  for (int f = 0; f < 2; ++f)
    #pragma unroll
    for (int ks = 0; ks < 4; ++ks)
      qf[f][ks] = *(const bf16x8*)(qk +
          (size_t)(bg * 1024 + qt * 64 + qw * 32 + f * 16 + lm) * 256 + ks * 32 + lg * 8);

  f32x4 oacc[2][16];
  #pragma unroll
  for (int f = 0; f < 2; ++f)
    #pragma unroll
    for (int hc = 0; hc < 16; ++hc) oacc[f][hc] = FZ;
  float m_run[2] = {-3e38f, -3e38f}, l_run[2] = {0.f, 0.f};

  const char* qkc = (const char*)qk;
  const char* vtc = (const char*)vt;
  const int krow = t >> 4;
  const char* ksrc = qkc + (size_t)(bg * 1024 + krow) * 512 + 256 + (((t & 15) ^ (krow & 7)) << 4);
  const char* vsrc = vtc + ((size_t)(bg * 1024 + (t >> 2))) * 2048 + (((t & 3) ^ ((t >> 3) & 3)) << 4);
  const int src0 = (2 * (lg & 1)) * 16 + lm;   // shuffle sources for P transform
  const int src1 = src0 + 16;
  const bool chlo = (lg < 2);

  // stage kv-tile `kv0` into buffer `buf` (9 gll16 per wave)
  auto stage = [&](int buf, int kv0) {
    gll16(ksrc + (size_t)kv0 * 512, sKc + buf * 8192 + w * 1024);
    char* vd = sVc + buf * 65536 + w * 1024;
    #pragma unroll
    for (int i = 0; i < 8; ++i)
      gll16(vsrc + (size_t)kv0 * 2 + 262144 * i, vd + 8192 * i);
  };

  int cur = 0;
  stage(0, 0);
  for (int kv0 = 0; kv0 < 1024; kv0 += 32) {
    // barrier 1: all waves done reading the buffer we are about to overwrite
    __builtin_amdgcn_s_barrier();
    __builtin_amdgcn_sched_barrier(0);
    if (kv0 + 32 < 1024) {
      stage(cur ^ 1, kv0 + 32);
      asm volatile("s_waitcnt vmcnt(9)" ::: "memory");  // cur landed; next 9 in flight
    } else {
      asm volatile("s_waitcnt vmcnt(0)" ::: "memory");
    }
    __builtin_amdgcn_sched_barrier(0);
    // barrier 2: every wave has its cur-tile loads landed -> tile visible to all
    __builtin_amdgcn_s_barrier();
    __builtin_amdgcn_sched_barrier(0);

    const char* sKb = sKc + cur * 8192;
    const char* sVb = sVc + cur * 65536;

    // S^T = K @ Q^T  (swapped operands)
    f32x4 sc[2][2];
    sc[0][0] = FZ; sc[0][1] = FZ; sc[1][0] = FZ; sc[1][1] = FZ;
    __builtin_amdgcn_s_setprio(1);
    #pragma unroll
    for (int ch = 0; ch < 2; ++ch)
      #pragma unroll
      for (int ks = 0; ks < 4; ++ks) {
        bf16x8 kf = *(const bf16x8*)(sKb + (ch * 16 + lm) * 256 + ((ks * 64 + lg * 16) ^ ((lm & 7) << 4)));
        sc[0][ch] = __builtin_amdgcn_mfma_f32_16x16x32_bf16(kf, qf[0][ks], sc[0][ch], 0, 0, 0);
        sc[1][ch] = __builtin_amdgcn_mfma_f32_16x16x32_bf16(kf, qf[1][ks], sc[1][ch], 0, 0, 0);
      }
    __builtin_amdgcn_s_setprio(0);

    // in-register online softmax (per-lane column q=lm; reduce across lg via 2 shuffles)
    float pm[2];
    #pragma unroll
    for (int f = 0; f < 2; ++f) {
      float a0 = fmaxf(fmaxf(sc[f][0][0], sc[f][0][1]), fmaxf(sc[f][0][2], sc[f][0][3]));
      float a1 = fmaxf(fmaxf(sc[f][1][0], sc[f][1][1]), fmaxf(sc[f][1][2], sc[f][1][3]));
      float m8 = fmaxf(a0, a1);
      m8 = fmaxf(m8, __shfl_xor(m8, 16));
      m8 = fmaxf(m8, __shfl_xor(m8, 32));
      pm[f] = m8;
    }
    const bool grow = (pm[0] > m_run[0] + 8.0f) | (pm[1] > m_run[1] + 8.0f);
    if (__any(grow)) {  // defer-max rescale (rare)
      #pragma unroll
      for (int f = 0; f < 2; ++f) {
        const float mn = fmaxf(m_run[f], pm[f]);
        const float alf = __expf(m_run[f] - mn);
        m_run[f] = mn;
        l_run[f] *= alf;
        float ab[4];
        #pragma unroll
        for (int j = 0; j < 4; ++j) ab[j] = __shfl(alf, lg * 4 + j);
        #pragma unroll
        for (int hc = 0; hc < 16; ++hc)
          #pragma unroll
          for (int j = 0; j < 4; ++j) oacc[f][hc][j] *= ab[j];
      }
    }

    // P = exp(S - m), row-sum, and in-register D->A transform (no LDS, no barrier)
    bf16x8 pa[2];
    #pragma unroll
    for (int f = 0; f < 2; ++f) {
      float p0[4], p1[4];
      #pragma unroll
      for (int j = 0; j < 4; ++j) {
        p0[j] = __expf(sc[f][0][j] - m_run[f]);
        p1[j] = __expf(sc[f][1][j] - m_run[f]);
      }
      float rs = ((p0[0] + p0[1]) + (p0[2] + p0[3])) + ((p1[0] + p1[1]) + (p1[2] + p1[3]));
      rs += __shfl_xor(rs, 16);
      rs += __shfl_xor(rs, 32);
      l_run[f] += rs;
      unsigned c0 = pkbf(p0[0], p0[1]);
      unsigned c1 = pkbf(p0[2], p0[3]);
      unsigned c2 = pkbf(p1[0], p1[1]);
      unsigned c3 = pkbf(p1[2], p1[3]);
      unsigned a0 = __shfl(c0, src0), b0 = __shfl(c2, src0);
      unsigned a1 = __shfl(c1, src0), b1 = __shfl(c3, src0);
      unsigned a2 = __shfl(c0, src1), b2 = __shfl(c2, src1);
      unsigned a3 = __shfl(c1, src1), b3 = __shfl(c3, src1);
      u32x4 pw;
      pw.x = chlo ? a0 : b0;
      pw.y = chlo ? a1 : b1;
      pw.z = chlo ? a2 : b2;
      pw.w = chlo ? a3 : b3;
      pa[f] = __builtin_bit_cast(bf16x8, pw);
    }

    // O += P @ V   (vf reused across both P fragments)
    __builtin_amdgcn_s_setprio(1);
    #pragma unroll
    for (int hc = 0; hc < 16; ++hc) {
      bf16x8 vf = *(const bf16x8*)(sVb + (hw * 256 + hc * 16 + lm) * 64 + ((lg * 16) ^ swzb));
      oacc[0][hc] = __builtin_amdgcn_mfma_f32_16x16x32_bf16(pa[0], vf, oacc[0][hc], 0, 0, 0);
      oacc[1][hc] = __builtin_amdgcn_mfma_f32_16x16x32_bf16(pa[1], vf, oacc[1][hc], 0, 0, 0);
    }
    __builtin_amdgcn_s_setprio(0);
    cur ^= 1;
  }

  // epilogue: out = gamma * O/l + x
  const float g0 = gam[0];
  #pragma unroll
  for (int f = 0; f < 2; ++f) {
    float inv[4];
    #pragma unroll
    for (int j = 0; j < 4; ++j) inv[j] = 1.0f / __shfl(l_run[f], lg * 4 + j);
    #pragma unroll
    for (int j = 0; j < 4; ++j) {
      const size_t ro = (size_t)(bg * 1024 + qt * 64 + qw * 32 + f * 16 + lg * 4 + j) * 1024;
      #pragma unroll
      for (int hc = 0; hc < 16; ++hc) {
        const int col = hw * 256 + hc * 16 + lm;
        out[ro + col] = g0 * oacc[f][hc][j] * inv[j] + x[ro + col];
      }
    }
  }
}

extern "C" void kernel_launch(void* const* d_in, const int* in_sizes, int n_in,
                              void* d_out, int out_size, void* d_ws, size_t ws_size,
                              hipStream_t stream) {
  const float* x  = (const float*)d_in[0];
  const float* Wq = (const float*)d_in[1];
  const float* bq = (const float*)d_in[2];
  const float* Wk = (const float*)d_in[3];
  const float* bk = (const float*)d_in[4];
  const float* Wv = (const float*)d_in[5];
  const float* bv = (const float*)d_in[6];
  const float* gm = (const float*)d_in[7];
  float* out = (float*)d_out;

  char* ws = (char*)d_ws;
  u16*   wt = (u16*)(ws);                 // 2,621,440 B
  float* bc = (float*)(ws + 2621440);     // 5,120 B
  u16*   qk = (u16*)(ws + 2626560);       // 16,777,216 B
  u16*   vt = (u16*)(ws + 19403776);      // 67,108,864 B

  build_bias_k<<<5, 256, 0, stream>>>(bq, bk, bv, bc);
  transpose_w_k<<<dim3(20, 16), 256, 0, stream>>>(Wq, Wk, Wv, wt);
  gemm_qkv_k<<<dim3(256, 2), 256, 0, stream>>>(x, wt, bc, qk, vt);
  attn_k<<<dim3(512), 512, 0, stream>>>(qk, vt, x, gm, out);
}